// Round 1
// baseline (348.018 us; speedup 1.0000x reference)
//
#include <hip/hip_runtime.h>

// Morphological opening: dilate3x3(erode3x3(x)), flat SE, SAME padding.
// v4: shuffle-free halo — each thread loads its full 8-col window directly
// (float4 at c0, float2 at c0-2, float2 at c0+4; clamped + select at edges).
// Overlapping float2 loads hit L1 (same lines as the wave's float4 loads),
// so HBM traffic is unchanged while the ds_bpermute/lgkmcnt dependency
// chain of v3 disappears entirely.
//
// Semantics: erosion pads OOB *inputs* with +inf (identity for min);
// erosion values at OOB *positions* enter the dilation max as -inf.

#define W 1024
#define H 1024
#define ROWS 16
#define NT 256

typedef float nvec4 __attribute__((ext_vector_type(4)));  // native vector for nontemporal store

struct Row { float4 m; float l0, l1, r0, r1; };

__global__ __launch_bounds__(NT)
void open3x3_v4(const float* __restrict__ in, float* __restrict__ out) {
    const int t  = threadIdx.x;
    const int c0 = 4 * t;                     // thread owns cols [c0, c0+4)
    const int y0 = blockIdx.x * ROWS;
    const size_t imgoff = (size_t)blockIdx.y * (size_t)(W * H);
    const float* img  = in  + imgoff;
    float*       outp = out + imgoff;

    const float PINF = __builtin_inff();
    const float NINF = -__builtin_inff();
    const bool has_l = (c0 > 0);              // position c0-1 valid; cols c0-2.. exist
    const bool has_r = (c0 + 4 < W);          // position c0+4 valid; cols c0+4.. exist
    const int  cl    = has_l ? c0 - 2 : 0;    // always-valid clamped halo addresses
    const int  cr    = has_r ? c0 + 4 : W - 4;

    // Load raw input row r: 8-float window c0-2..c0+5 per thread. OOB -> +inf.
    auto load_row = [&](int r) -> Row {
        Row R;
        if (r >= 0 && r < H) {                // block-uniform branch
            const float* p = img + r * W;
            R.m = *(const float4*)(p + c0);
            float2 L  = *(const float2*)(p + cl);
            float2 Rr = *(const float2*)(p + cr);
            R.l0 = has_l ? L.x  : PINF;
            R.l1 = has_l ? L.y  : PINF;
            R.r0 = has_r ? Rr.x : PINF;
            R.r1 = has_r ? Rr.y : PINF;
        } else {
            R.m = make_float4(PINF, PINF, PINF, PINF);
            R.l0 = R.l1 = R.r0 = R.r1 = PINF;
        }
        return R;
    };

    // Horizontal 3-min over the 8-col window c0-2..c0+5 -> hm[0..5] at positions c0-1..c0+4.
    auto hmin6 = [&](const Row& R, float hm[6]) {
        const float x0 = R.l0, x1 = R.l1;
        const float x2 = R.m.x, x3 = R.m.y, x4 = R.m.z, x5 = R.m.w;
        const float x6 = R.r0, x7 = R.r1;
        hm[0] = fminf(fminf(x0, x1), x2);
        hm[1] = fminf(fminf(x1, x2), x3);
        hm[2] = fminf(fminf(x2, x3), x4);
        hm[3] = fminf(fminf(x3, x4), x5);
        hm[4] = fminf(fminf(x4, x5), x6);
        hm[5] = fminf(fminf(x5, x6), x7);
    };

    // Erosion row r at positions c0-1..c0+4; OOB row/col positions -> -inf.
    auto erow = [&](int r, const float a[6], const float b[6], const float c[6], float e[6]) {
        if (r >= 0 && r < H) {                // block-uniform branch
            #pragma unroll
            for (int i = 0; i < 6; i++) e[i] = fminf(fminf(a[i], b[i]), c[i]);
            if (!has_l) e[0] = NINF;
            if (!has_r) e[5] = NINF;
        } else {
            #pragma unroll
            for (int i = 0; i < 6; i++) e[i] = NINF;
        }
    };

    auto hmax4 = [&](const float e[6], float hx[4]) {
        #pragma unroll
        for (int i = 0; i < 4; i++) hx[i] = fmaxf(fmaxf(e[i], e[i + 1]), e[i + 2]);
    };

    // ---- prologue: issue 7 independent loads up front ----
    Row r0 = load_row(y0 - 2);
    Row r1 = load_row(y0 - 1);
    Row r2 = load_row(y0);
    Row r3 = load_row(y0 + 1);
    Row buf[3];
    buf[0] = load_row(y0 + 2);
    buf[1] = load_row(y0 + 3);
    buf[2] = load_row(y0 + 4);

    float hmA[6], hmB[6], hmC[6], hmD[6];
    hmin6(r0, hmA); hmin6(r1, hmB); hmin6(r2, hmC); hmin6(r3, hmD);
    float e[6], hx0[4], hx1[4], hx2[4];
    erow(y0 - 1, hmA, hmB, hmC, e); hmax4(e, hx0);
    erow(y0,     hmB, hmC, hmD, e); hmax4(e, hx1);
    float hmP[6], hmQ[6], hmR[6];
    #pragma unroll
    for (int i = 0; i < 6; i++) { hmP[i] = hmC[i]; hmQ[i] = hmD[i]; }

    // ---- fully-unrolled main loop: compute output row y, prefetch raw row y+5 ----
    #pragma unroll
    for (int k = 0; k < ROWS; k++) {
        const int y = y0 + k;
        Row cur = buf[k % 3];                 // raw(y+2), loaded 3 iterations ago
        if (k < ROWS - 3) buf[k % 3] = load_row(y + 5);

        hmin6(cur, hmR);                      // hmin(y+2)
        erow(y + 1, hmP, hmQ, hmR, e);        // erosion row y+1
        hmax4(e, hx2);

        nvec4 o;
        o.x = fmaxf(fmaxf(hx0[0], hx1[0]), hx2[0]);
        o.y = fmaxf(fmaxf(hx0[1], hx1[1]), hx2[1]);
        o.z = fmaxf(fmaxf(hx0[2], hx1[2]), hx2[2]);
        o.w = fmaxf(fmaxf(hx0[3], hx1[3]), hx2[3]);
        __builtin_nontemporal_store(o, (nvec4*)(outp + (size_t)y * W + c0));

        #pragma unroll
        for (int i = 0; i < 4; i++) { hx0[i] = hx1[i]; hx1[i] = hx2[i]; }
        #pragma unroll
        for (int i = 0; i < 6; i++) { hmP[i] = hmQ[i]; hmQ[i] = hmR[i]; }
    }
}

extern "C" void kernel_launch(void* const* d_in, const int* in_sizes, int n_in,
                              void* d_out, int out_size, void* d_ws, size_t ws_size,
                              hipStream_t stream) {
    const float* x = (const float*)d_in[0];
    float* out = (float*)d_out;
    // 16 batch * 3 channels = 48 images; 64 row-tiles per image -> 3072 blocks
    dim3 grid(H / ROWS, 48);
    dim3 block(NT);
    open3x3_v4<<<grid, block, 0, stream>>>(x, out);
}

// Round 2
// 343.046 us; speedup vs baseline: 1.0145x; 1.0145x over previous
//
#include <hip/hip_runtime.h>

// Morphological opening: dilate3x3(erode3x3(x)), flat SE, SAME padding.
// v5: v4 + (a) sched_barrier-pinned prefetch ring — rocprof showed VGPR=32,
// proving the compiler sank the ring loads to their uses and destroyed the
// 3-row prefetch distance (VALUBusy 12%, HBM 32% => latency-bound);
// (b) 2 overlapping float4 loads per row (8B-aligned) instead of
// float4+2xfloat2 — one less VMEM op per row, edge remap via uniform selects.
//
// Semantics: erosion pads OOB *inputs* with +inf (identity for min);
// erosion values at OOB *positions* enter the dilation max as -inf.

#define W 1024
#define H 1024
#define ROWS 16
#define NT 256

typedef float nvec4 __attribute__((ext_vector_type(4)));  // native vector for nontemporal store

struct Row { float4 A, B; };  // cols c0-2..c0+1 and c0+2..c0+5 (interior mapping)

__global__ __launch_bounds__(NT, 2)
void open3x3_v5(const float* __restrict__ in, float* __restrict__ out) {
    const int t  = threadIdx.x;
    const int c0 = 4 * t;                     // thread owns cols [c0, c0+4)
    const int y0 = blockIdx.x * ROWS;
    const size_t imgoff = (size_t)blockIdx.y * (size_t)(W * H);
    const float* img  = in  + imgoff;
    float*       outp = out + imgoff;

    const float PINF = __builtin_inff();
    const float NINF = -__builtin_inff();
    const bool has_l = (c0 > 0);              // position c0-1 valid; cols c0-2.. exist
    const bool has_r = (c0 + 4 < W);          // position c0+4 valid; cols c0+4.. exist
    const int  cla   = has_l ? c0 - 2 : 0;    // clamped 8B-aligned halo bases
    const int  crb   = has_r ? c0 + 2 : W - 4;

    // Load raw input row r: two overlapping float4s covering cols c0-2..c0+5.
    auto load_row = [&](int r) -> Row {
        Row R;
        if (r >= 0 && r < H) {                // block-uniform branch
            const float* p = img + r * W;
            R.A = *(const float4*)(p + cla);
            R.B = *(const float4*)(p + crb);
        } else {
            R.A = make_float4(PINF, PINF, PINF, PINF);
            R.B = R.A;
        }
        return R;
    };

    // Horizontal 3-min over the 8-col window -> hm[0..5] at positions c0-1..c0+4.
    // Edge remap: uniform per-thread selects (only the extreme threads differ).
    auto hmin6 = [&](const Row& R, float hm[6]) {
        const float x0 = has_l ? R.A.x : PINF;
        const float x1 = has_l ? R.A.y : PINF;
        const float x2 = has_l ? R.A.z : R.A.x;
        const float x3 = has_l ? R.A.w : R.A.y;
        const float x4 = has_r ? R.B.x : R.B.z;
        const float x5 = has_r ? R.B.y : R.B.w;
        const float x6 = has_r ? R.B.z : PINF;
        const float x7 = has_r ? R.B.w : PINF;
        hm[0] = fminf(fminf(x0, x1), x2);
        hm[1] = fminf(fminf(x1, x2), x3);
        hm[2] = fminf(fminf(x2, x3), x4);
        hm[3] = fminf(fminf(x3, x4), x5);
        hm[4] = fminf(fminf(x4, x5), x6);
        hm[5] = fminf(fminf(x5, x6), x7);
    };

    // Erosion row r at positions c0-1..c0+4; OOB row/col positions -> -inf.
    auto erow = [&](int r, const float a[6], const float b[6], const float c[6], float e[6]) {
        if (r >= 0 && r < H) {                // block-uniform branch
            #pragma unroll
            for (int i = 0; i < 6; i++) e[i] = fminf(fminf(a[i], b[i]), c[i]);
            if (!has_l) e[0] = NINF;
            if (!has_r) e[5] = NINF;
        } else {
            #pragma unroll
            for (int i = 0; i < 6; i++) e[i] = NINF;
        }
    };

    auto hmax4 = [&](const float e[6], float hx[4]) {
        #pragma unroll
        for (int i = 0; i < 4; i++) hx[i] = fmaxf(fmaxf(e[i], e[i + 1]), e[i + 2]);
    };

    // ---- prologue: issue 7 independent row loads up front, pin them there ----
    Row r0 = load_row(y0 - 2);
    Row r1 = load_row(y0 - 1);
    Row r2 = load_row(y0);
    Row r3 = load_row(y0 + 1);
    Row buf[3];
    buf[0] = load_row(y0 + 2);
    buf[1] = load_row(y0 + 3);
    buf[2] = load_row(y0 + 4);
    __builtin_amdgcn_sched_barrier(0);        // keep all 14 loads issued before compute

    float hmA[6], hmB[6], hmC[6], hmD[6];
    hmin6(r0, hmA); hmin6(r1, hmB); hmin6(r2, hmC); hmin6(r3, hmD);
    float e[6], hx0[4], hx1[4], hx2[4];
    erow(y0 - 1, hmA, hmB, hmC, e); hmax4(e, hx0);
    erow(y0,     hmB, hmC, hmD, e); hmax4(e, hx1);
    float hmP[6], hmQ[6], hmR[6];
    #pragma unroll
    for (int i = 0; i < 6; i++) { hmP[i] = hmC[i]; hmQ[i] = hmD[i]; }

    // ---- fully-unrolled main loop: compute output row y, prefetch raw row y+5 ----
    #pragma unroll
    for (int k = 0; k < ROWS; k++) {
        const int y = y0 + k;
        Row cur = buf[k % 3];                 // raw(y+2), loaded 3 iterations ago
        if (k < ROWS - 3) buf[k % 3] = load_row(y + 5);
        __builtin_amdgcn_sched_barrier(0);    // prefetch may not sink below compute

        hmin6(cur, hmR);                      // hmin(y+2)
        erow(y + 1, hmP, hmQ, hmR, e);        // erosion row y+1
        hmax4(e, hx2);

        nvec4 o;
        o.x = fmaxf(fmaxf(hx0[0], hx1[0]), hx2[0]);
        o.y = fmaxf(fmaxf(hx0[1], hx1[1]), hx2[1]);
        o.z = fmaxf(fmaxf(hx0[2], hx1[2]), hx2[2]);
        o.w = fmaxf(fmaxf(hx0[3], hx1[3]), hx2[3]);
        __builtin_nontemporal_store(o, (nvec4*)(outp + (size_t)y * W + c0));

        #pragma unroll
        for (int i = 0; i < 4; i++) { hx0[i] = hx1[i]; hx1[i] = hx2[i]; }
        #pragma unroll
        for (int i = 0; i < 6; i++) { hmP[i] = hmQ[i]; hmQ[i] = hmR[i]; }
    }
}

extern "C" void kernel_launch(void* const* d_in, const int* in_sizes, int n_in,
                              void* d_out, int out_size, void* d_ws, size_t ws_size,
                              hipStream_t stream) {
    const float* x = (const float*)d_in[0];
    float* out = (float*)d_out;
    // 16 batch * 3 channels = 48 images; 64 row-tiles per image -> 3072 blocks
    dim3 grid(H / ROWS, 48);
    dim3 block(NT);
    open3x3_v5<<<grid, block, 0, stream>>>(x, out);
}